// Round 21
// baseline (81.386 us; speedup 1.0000x reference)
//
#include <hip/hip_runtime.h>

#define IMG 65536   // 256*256
#define W 256
#define H 256
#define RMAX 40     // truncated radius cap (t=19 tail at 40: ~2.6e-6 < 1e-5 budget)

// d_ws layout:
//   ktab: 20 x 256 floats (truncated, renormalized composed kernels; tap j at [8+j]), bytes [0, 20480)
//   ord : 192 ints at byte 20480 (images sorted by t desc)
//   rtab: 20 ints at byte 21248 (truncated radius per t, <= RMAX)
//   mid : 192*65536 floats at byte 32768 (intermediate H-pass output)

__global__ __launch_bounds__(256) void init_kernel(const int* __restrict__ t,
                                                   float* __restrict__ ktab,
                                                   int* __restrict__ ord,
                                                   int* __restrict__ rtab) {
  __shared__ double cur[256];
  __shared__ double sc[256];    // prefix-sum scratch
  __shared__ double base[11];
  __shared__ int keys[192];
  __shared__ int sRmax;
  int tid = threadIdx.x;
  int tt = blockIdx.x;          // 0..19
  if (tid == 0) {
    double p[11];
    double s = 0.0;
    for (int i = 0; i < 11; ++i) {
      double xx = (double)(i - 5) * 0.5;       // x / SIGMA, SIGMA=2
      p[i] = exp(-0.5 * xx * xx);
      s += p[i];
    }
    for (int i = 0; i < 11; ++i) base[i] = (double)(float)(p[i] / s);  // match np float32 taps
  }
  __syncthreads();

  if (tt == 0) {
    // identity kernel row (t=0 safety) + rank-sort images by t desc
    ktab[tid] = (tid == 8) ? 1.0f : 0.0f;
    if (tid == 0) rtab[0] = 0;
    if (tid < 192) keys[tid] = min(max(t[tid / 3], 0), 19);
    __syncthreads();
    if (tid < 192) {
      int k = keys[tid];
      int rank = 0;
      for (int j = 0; j < 192; ++j) {
        int kj = keys[j];
        if (kj > k || (kj == k && j < tid)) ++rank;
      }
      ord[rank] = tid;
    }
    return;
  }

  cur[tid] = (tid < 11) ? base[tid] : 0.0;
  __syncthreads();
  for (int step = 2; step <= tt; ++step) {
    int Lprev = 10 * (step - 1) + 1;
    double a = 0.0;
    for (int i = 0; i < 11; ++i) {
      int jj = tid - i;
      if (jj >= 0 && jj < Lprev) a += base[i] * cur[jj];
    }
    __syncthreads();
    cur[tid] = a;
    __syncthreads();
  }
  // parallel inclusive prefix sum of cur -> sc (Hillis-Steele, 8 steps)
  sc[tid] = cur[tid];
  __syncthreads();
#pragma unroll
  for (int off = 1; off < 256; off <<= 1) {
    double tmp = (tid >= off) ? sc[tid - off] : 0.0;
    __syncthreads();
    sc[tid] += tmp;
    __syncthreads();
  }
  if (tid == 0) sRmax = 1;
  __syncthreads();
  // truncation: R = max r in [1,5t] with tail-outside-(r-1) > 1e-5  (monotone)
  int c = 5 * tt;
  double total = sc[255];
  if (tid >= 1 && tid <= c) {
    double Srm1 = sc[c + tid - 1] - sc[c - tid];     // window sum, radius tid-1
    if (total - Srm1 > 1e-5) atomicMax(&sRmax, tid);
  }
  __syncthreads();
  int Rk = min(sRmax, RMAX);                         // cap for staged-halo kernels
  double ksum = sc[c + Rk] - ((c - Rk - 1 >= 0) ? sc[c - Rk - 1] : 0.0);
  double scale = 1.0 / ksum;                         // renormalize kept mass to 1
  if (tid == 0) rtab[tt] = Rk;
  int c0 = c - Rk;
  int Lk = 2 * Rk + 1;
  ktab[tt * 256 + tid] =
      (tid >= 8 && tid < 8 + Lk) ? (float)(cur[tid - 8 + c0] * scale) : 0.0f;
}

// H-pass (r18 structure + ROUND-21 SOFTWARE PIPELINE): 32-col transposed tile
// [32][352] b128 reads, dual-window (+128), d-shifted taps, 16B-chunk XOR
// swizzle on both stage and read, (256,3), grid (8,192).
// PIPELINE RATIONALE: taps via s_load share lgkmcnt with ds_reads and return
// out-of-order -> first FMA's wait forced lgkmcnt(0), one full drain per
// 1024-cyc jb-block, synchronized across waves (VALUBusy 31%). Now block
// jb+16's taps+reads are ISSUED before block jb's FMAs consume buffered
// values -> waits land ~1024 cyc after issue. Accumulation order unchanged.
__global__ __launch_bounds__(256, 3) void hpass_kernel(const float* __restrict__ x,
                                                       const int* __restrict__ t,
                                                       const float* __restrict__ ktab,
                                                       const int* __restrict__ ord,
                                                       const int* __restrict__ rtab,
                                                       float* __restrict__ out) {
  __shared__ float tile[32 * 352];            // transposed: [col][r], 45 KB -> 3/CU
  int tid = threadIdx.x;
  int img = __builtin_amdgcn_readfirstlane(ord[blockIdx.y]);
  int wt = blockIdx.x;                        // 0..7
  int b = img / 3;
  int tv = __builtin_amdgcn_readfirstlane(min(max(t[b], 0), 19));
  int R = __builtin_amdgcn_readfirstlane(rtab[tv]);
  int L = 2 * R + 1;
  int d = (RMAX - R) & 3;
  const float* __restrict__ kt = ktab + tv * 256 + (8 - d);  // d-shifted tap base
  const float* src = x + (size_t)img * IMG + (wt << 5);
  float* dst = out + (size_t)img * IMG + (wt << 5);
  {
    int c4 = (tid & 7) << 2;                  // 0..28
    int r0 = tid >> 3;                        // 0..31
#pragma unroll
    for (int i = 0; i < 11; ++i) {
      int rr = r0 + (i << 5);                 // 0..351
      int p = rr - RMAX;                      // -40..311
      int srow = 255 - abs(255 - abs(p));     // reflect (valid for |p| <= 510)
      float4 v = *reinterpret_cast<const float4*>(src + srow * W + c4);
      int rc = rr & ~3, rl = rr & 3;
      tile[(c4 + 0) * 352 + (rc ^ (((c4 + 0) & 7) << 2)) + rl] = v.x;
      tile[(c4 + 1) * 352 + (rc ^ (((c4 + 1) & 7) << 2)) + rl] = v.y;
      tile[(c4 + 2) * 352 + (rc ^ (((c4 + 2) & 7) << 2)) + rl] = v.z;
      tile[(c4 + 3) * 352 + (rc ^ (((c4 + 3) & 7) << 2)) + rl] = v.w;
    }
  }
  __syncthreads();
  int col = tid & 31;
  int rgrp = tid >> 5;                        // 0..7
  int h0 = rgrp << 4;                         // window A rows h0..h0+15; B = +128
  int nIter = (L + d + 30) & ~15;             // >= L+d+15: covers j=L-1 for o=15
  int A = h0 + ((RMAX - R) & ~3);             // aligned sweep start (tile coords)
  int cb = col * 352;
  int swz = (col & 7) << 2;
  float accA[16], accB[16], kq[16];
#pragma unroll
  for (int o = 0; o < 16; ++o) { accA[o] = 0.f; accB[o] = 0.f; kq[o] = 0.f; }
  // --- software pipeline: current-block buffers, loaded in prologue ---
  float knC[16], vaC[16], vbC[16];
#pragma unroll
  for (int u = 0; u < 16; ++u) knC[u] = kt[u];
#pragma unroll
  for (int m = 0; m < 4; ++m) {
    int qa = A + (m << 2);
    float4 ta = *reinterpret_cast<const float4*>(&tile[cb + (qa ^ swz)]);
    float4 tb = *reinterpret_cast<const float4*>(&tile[cb + ((qa + 128) ^ swz)]);
    vaC[4 * m + 0] = ta.x; vaC[4 * m + 1] = ta.y; vaC[4 * m + 2] = ta.z; vaC[4 * m + 3] = ta.w;
    vbC[4 * m + 0] = tb.x; vbC[4 * m + 1] = tb.y; vbC[4 * m + 2] = tb.z; vbC[4 * m + 3] = tb.w;
  }
  for (int jb = 0; jb < nIter; jb += 16) {
    // issue NEXT block's loads first (branchless wrap keeps addresses valid)
    int jn = (jb + 16 < nIter) ? (jb + 16) : 0;
    float knN[16], vaN[16], vbN[16];
#pragma unroll
    for (int u = 0; u < 16; ++u) knN[u] = kt[jn + u];
#pragma unroll
    for (int m = 0; m < 4; ++m) {
      int qa = A + jn + (m << 2);
      float4 ta = *reinterpret_cast<const float4*>(&tile[cb + (qa ^ swz)]);
      float4 tb = *reinterpret_cast<const float4*>(&tile[cb + ((qa + 128) ^ swz)]);
      vaN[4 * m + 0] = ta.x; vaN[4 * m + 1] = ta.y; vaN[4 * m + 2] = ta.z; vaN[4 * m + 3] = ta.w;
      vbN[4 * m + 0] = tb.x; vbN[4 * m + 1] = tb.y; vbN[4 * m + 2] = tb.z; vbN[4 * m + 3] = tb.w;
    }
    // FMA block consumes previously-loaded buffers (waits already satisfied)
#pragma unroll
    for (int u = 0; u < 16; ++u) {
      kq[u] = knC[u];
#pragma unroll
      for (int o = 0; o < 16; ++o) {
        float k = kq[(u - o) & 15];
        accA[o] += k * vaC[u];
        accB[o] += k * vbC[u];
      }
    }
    // rotate buffers
#pragma unroll
    for (int u = 0; u < 16; ++u) { knC[u] = knN[u]; vaC[u] = vaN[u]; vbC[u] = vbN[u]; }
  }
#pragma unroll
  for (int o = 0; o < 16; ++o) {
    dst[(h0 + o) * W + col] = accA[o];
    dst[(h0 + 128 + o) * W + col] = accB[o];
  }
}

// W-pass (r14 BEST-MEASURED, verbatim): tile[32][361] (stride coprime to 32 ->
// conflict-free same-col reads), taps broadcast from ktile LDS, dual g-loop,
// float4 stores, (256,3), grid (8,192). DO NOT TOUCH (protecting measured win).
__global__ __launch_bounds__(256, 3) void wpass_split(const float* __restrict__ srcbuf,
                                                      const int* __restrict__ t,
                                                      const float* __restrict__ ktab,
                                                      const int* __restrict__ ord,
                                                      const int* __restrict__ rtab,
                                                      float* __restrict__ dstbuf) {
  __shared__ float tile[32 * 361];
  __shared__ float ktile[256];
  int tid = threadIdx.x;
  int img = __builtin_amdgcn_readfirstlane(ord[blockIdx.y]);
  int ht = blockIdx.x;                        // 0..7
  int b = img / 3;
  int tv = __builtin_amdgcn_readfirstlane(min(max(t[b], 0), 19));
  int R = __builtin_amdgcn_readfirstlane(rtab[tv]);
  int L = 2 * R + 1;
  const float* __restrict__ kt = ktab + tv * 256;
  const float* src = srcbuf + (size_t)img * IMG + (ht << 5) * W;
  float* dst = dstbuf + (size_t)img * IMG + (ht << 5) * W;
  ktile[tid] = kt[tid];                       // tap row -> LDS (1 KB)
  {
    int srow = tid >> 3;                      // 0..31
    int jbase = tid & 7;
    const float* sp = src + srow * W;
    float* tp0 = &tile[srow * 361];
#pragma unroll
    for (int k = 0; k < 11; ++k) {
      int j = jbase + (k << 3);               // 0..87
      int c0 = -RMAX + (j << 2);              // -40..308
      float* tp = tp0 + c0 + RMAX;
      if (c0 >= 0 && c0 <= 252) {
        float4 v = *reinterpret_cast<const float4*>(sp + c0);
        tp[0] = v.x; tp[1] = v.y; tp[2] = v.z; tp[3] = v.w;
      } else {
#pragma unroll
        for (int d = 0; d < 4; ++d) {
          int cc = c0 + d;
          int rc = 255 - abs(255 - abs(cc));  // reflect
          tp[d] = sp[rc];
        }
      }
    }
  }
  __syncthreads();
  int row = tid & 31;
  int wgrp = tid >> 5;                        // 0..7
  int rowbase = row * 361;
  int nIter = (L + 30) & ~15;
  for (int g = 0; g < 2; ++g) {
    int w0 = (wgrp << 5) + (g << 4);
    float acc[16];
    float kq[16];
#pragma unroll
    for (int o = 0; o < 16; ++o) { acc[o] = 0.f; kq[o] = 0.f; }
    int pb = w0 - R + RMAX;                   // tile-col base (>= 0; reads <= 350 < 361)
    for (int jb = 0; jb < nIter; jb += 16) {
#pragma unroll
      for (int u = 0; u < 16; ++u) {
        kq[u] = ktile[jb + u + 8];            // uniform addr -> LDS broadcast
        float v = tile[rowbase + pb + jb + u];
#pragma unroll
        for (int o = 0; o < 16; ++o) acc[o] += kq[(u - o) & 15] * v;
      }
    }
    float4 v0 = make_float4(acc[0], acc[1], acc[2], acc[3]);
    float4 v1 = make_float4(acc[4], acc[5], acc[6], acc[7]);
    float4 v2 = make_float4(acc[8], acc[9], acc[10], acc[11]);
    float4 v3 = make_float4(acc[12], acc[13], acc[14], acc[15]);
    float* o0 = dst + row * W + w0;
    *reinterpret_cast<float4*>(o0 + 0) = v0;
    *reinterpret_cast<float4*>(o0 + 4) = v1;
    *reinterpret_cast<float4*>(o0 + 8) = v2;
    *reinterpret_cast<float4*>(o0 + 12) = v3;
  }
}

// Fallback in-place W-pass (only if ws too small; same structure, io buffer).
__global__ __launch_bounds__(256, 3) void wpass_inplace(const int* __restrict__ t,
                                                        const float* __restrict__ ktab,
                                                        const int* __restrict__ ord,
                                                        const int* __restrict__ rtab,
                                                        float* __restrict__ io) {
  __shared__ float tile[32 * 361];
  __shared__ float ktile[256];
  int tid = threadIdx.x;
  int img = __builtin_amdgcn_readfirstlane(ord[blockIdx.y]);
  int ht = blockIdx.x;                        // 0..7
  int b = img / 3;
  int tv = __builtin_amdgcn_readfirstlane(min(max(t[b], 0), 19));
  int R = __builtin_amdgcn_readfirstlane(rtab[tv]);
  int L = 2 * R + 1;
  const float* __restrict__ kt = ktab + tv * 256;
  float* basep = io + (size_t)img * IMG + (ht << 5) * W;
  ktile[tid] = kt[tid];
  {
    int srow = tid >> 3;
    int jbase = tid & 7;
    const float* sp = basep + srow * W;
    float* tp0 = &tile[srow * 361];
#pragma unroll
    for (int k = 0; k < 11; ++k) {
      int j = jbase + (k << 3);
      int c0 = -RMAX + (j << 2);
      float* tp = tp0 + c0 + RMAX;
      if (c0 >= 0 && c0 <= 252) {
        float4 v = *reinterpret_cast<const float4*>(sp + c0);
        tp[0] = v.x; tp[1] = v.y; tp[2] = v.z; tp[3] = v.w;
      } else {
#pragma unroll
        for (int d = 0; d < 4; ++d) {
          int cc = c0 + d;
          int rc = 255 - abs(255 - abs(cc));
          tp[d] = sp[rc];
        }
      }
    }
  }
  __syncthreads();
  int row = tid & 31;
  int wgrp = tid >> 5;
  int rowbase = row * 361;
  int nIter = (L + 30) & ~15;
  for (int g = 0; g < 2; ++g) {
    int w0 = (wgrp << 5) + (g << 4);
    float acc[16];
    float kq[16];
#pragma unroll
    for (int o = 0; o < 16; ++o) { acc[o] = 0.f; kq[o] = 0.f; }
    int pb = w0 - R + RMAX;
    for (int jb = 0; jb < nIter; jb += 16) {
#pragma unroll
      for (int u = 0; u < 16; ++u) {
        kq[u] = ktile[jb + u + 8];
        float v = tile[rowbase + pb + jb + u];
#pragma unroll
        for (int o = 0; o < 16; ++o) acc[o] += kq[(u - o) & 15] * v;
      }
    }
    float4 v0 = make_float4(acc[0], acc[1], acc[2], acc[3]);
    float4 v1 = make_float4(acc[4], acc[5], acc[6], acc[7]);
    float4 v2 = make_float4(acc[8], acc[9], acc[10], acc[11]);
    float4 v3 = make_float4(acc[12], acc[13], acc[14], acc[15]);
    float* o0 = basep + row * W + w0;
    *reinterpret_cast<float4*>(o0 + 0) = v0;
    *reinterpret_cast<float4*>(o0 + 4) = v1;
    *reinterpret_cast<float4*>(o0 + 8) = v2;
    *reinterpret_cast<float4*>(o0 + 12) = v3;
  }
}

extern "C" void kernel_launch(void* const* d_in, const int* in_sizes, int n_in,
                              void* d_out, int out_size, void* d_ws, size_t ws_size,
                              hipStream_t stream) {
  const float* x = (const float*)d_in[0];
  const int* t = (const int*)d_in[1];
  float* out = (float*)d_out;
  float* ktab = (float*)d_ws;
  int* ord = (int*)((char*)d_ws + 20480);
  int* rtab = (int*)((char*)d_ws + 21248);
  const size_t mid_off = 32768;
  const size_t mid_bytes = (size_t)192 * IMG * 4;

  hipLaunchKernelGGL(init_kernel, dim3(20), dim3(256), 0, stream, t, ktab, ord, rtab);
  if (ws_size >= mid_off + mid_bytes) {
    float* mid = (float*)((char*)d_ws + mid_off);
    hipLaunchKernelGGL(hpass_kernel, dim3(8, 192), dim3(256), 0, stream, x, t, ktab, ord, rtab, mid);
    hipLaunchKernelGGL(wpass_split, dim3(8, 192), dim3(256), 0, stream, mid, t, ktab, ord, rtab, out);
  } else {
    hipLaunchKernelGGL(hpass_kernel, dim3(8, 192), dim3(256), 0, stream, x, t, ktab, ord, rtab, out);
    hipLaunchKernelGGL(wpass_inplace, dim3(8, 192), dim3(256), 0, stream, t, ktab, ord, rtab, out);
  }
}

// Round 22
// 80.111 us; speedup vs baseline: 1.0159x; 1.0159x over previous
//
#include <hip/hip_runtime.h>

#define IMG 65536   // 256*256
#define W 256
#define H 256
#define RMAX 40     // truncated radius cap (t=19 tail at 40: ~2.6e-6 < 1e-5 budget)

// d_ws layout:
//   ktab: 20 x 256 floats (truncated, renormalized composed kernels; tap j at [8+j]), bytes [0, 20480)
//   ord : 192 ints at byte 20480 (images sorted by t desc)
//   rtab: 20 ints at byte 21248 (truncated radius per t, <= RMAX)
//   mid : 192*65536 floats at byte 32768 (intermediate H-pass output)

__global__ __launch_bounds__(256) void init_kernel(const int* __restrict__ t,
                                                   float* __restrict__ ktab,
                                                   int* __restrict__ ord,
                                                   int* __restrict__ rtab) {
  __shared__ double cur[256];
  __shared__ double sc[256];    // prefix-sum scratch
  __shared__ double base[11];
  __shared__ int keys[192];
  __shared__ int sRmax;
  int tid = threadIdx.x;
  int tt = blockIdx.x;          // 0..19
  if (tid == 0) {
    double p[11];
    double s = 0.0;
    for (int i = 0; i < 11; ++i) {
      double xx = (double)(i - 5) * 0.5;       // x / SIGMA, SIGMA=2
      p[i] = exp(-0.5 * xx * xx);
      s += p[i];
    }
    for (int i = 0; i < 11; ++i) base[i] = (double)(float)(p[i] / s);  // match np float32 taps
  }
  __syncthreads();

  if (tt == 0) {
    // identity kernel row (t=0 safety) + rank-sort images by t desc
    ktab[tid] = (tid == 8) ? 1.0f : 0.0f;
    if (tid == 0) rtab[0] = 0;
    if (tid < 192) keys[tid] = min(max(t[tid / 3], 0), 19);
    __syncthreads();
    if (tid < 192) {
      int k = keys[tid];
      int rank = 0;
      for (int j = 0; j < 192; ++j) {
        int kj = keys[j];
        if (kj > k || (kj == k && j < tid)) ++rank;
      }
      ord[rank] = tid;
    }
    return;
  }

  cur[tid] = (tid < 11) ? base[tid] : 0.0;
  __syncthreads();
  for (int step = 2; step <= tt; ++step) {
    int Lprev = 10 * (step - 1) + 1;
    double a = 0.0;
    for (int i = 0; i < 11; ++i) {
      int jj = tid - i;
      if (jj >= 0 && jj < Lprev) a += base[i] * cur[jj];
    }
    __syncthreads();
    cur[tid] = a;
    __syncthreads();
  }
  // parallel inclusive prefix sum of cur -> sc (Hillis-Steele, 8 steps)
  sc[tid] = cur[tid];
  __syncthreads();
#pragma unroll
  for (int off = 1; off < 256; off <<= 1) {
    double tmp = (tid >= off) ? sc[tid - off] : 0.0;
    __syncthreads();
    sc[tid] += tmp;
    __syncthreads();
  }
  if (tid == 0) sRmax = 1;
  __syncthreads();
  // truncation: R = max r in [1,5t] with tail-outside-(r-1) > 1e-5  (monotone)
  int c = 5 * tt;
  double total = sc[255];
  if (tid >= 1 && tid <= c) {
    double Srm1 = sc[c + tid - 1] - sc[c - tid];     // window sum, radius tid-1
    if (total - Srm1 > 1e-5) atomicMax(&sRmax, tid);
  }
  __syncthreads();
  int Rk = min(sRmax, RMAX);                         // cap for staged-halo kernels
  double ksum = sc[c + Rk] - ((c - Rk - 1 >= 0) ? sc[c - Rk - 1] : 0.0);
  double scale = 1.0 / ksum;                         // renormalize kept mass to 1
  if (tid == 0) rtab[tt] = Rk;
  int c0 = c - Rk;
  int Lk = 2 * Rk + 1;
  ktab[tt * 256 + tid] =
      (tid >= 8 && tid < 8 + Lk) ? (float)(cur[tid - 8 + c0] * scale) : 0.0f;
}

// H-pass (r18/r20 BEST-MEASURED, verbatim): 32-col transposed tile [32][352]
// b128 reads, dual-window (+128), d-shifted taps into ktab's leading zeros,
// 16B-chunk XOR swizzle on both stage and read, (256,3), grid (8,192).
// r21's explicit software pipeline was falsified (neutral-negative) -> removed.
__global__ __launch_bounds__(256, 3) void hpass_kernel(const float* __restrict__ x,
                                                       const int* __restrict__ t,
                                                       const float* __restrict__ ktab,
                                                       const int* __restrict__ ord,
                                                       const int* __restrict__ rtab,
                                                       float* __restrict__ out) {
  __shared__ float tile[32 * 352];            // transposed: [col][r], 45 KB -> 3/CU
  int tid = threadIdx.x;
  int img = __builtin_amdgcn_readfirstlane(ord[blockIdx.y]);
  int wt = blockIdx.x;                        // 0..7
  int b = img / 3;
  int tv = __builtin_amdgcn_readfirstlane(min(max(t[b], 0), 19));
  int R = __builtin_amdgcn_readfirstlane(rtab[tv]);
  int L = 2 * R + 1;
  int d = (RMAX - R) & 3;
  const float* __restrict__ kt = ktab + tv * 256 + (8 - d);  // d-shifted tap base
  const float* src = x + (size_t)img * IMG + (wt << 5);
  float* dst = out + (size_t)img * IMG + (wt << 5);
  {
    int c4 = (tid & 7) << 2;                  // 0..28
    int r0 = tid >> 3;                        // 0..31
#pragma unroll
    for (int i = 0; i < 11; ++i) {
      int rr = r0 + (i << 5);                 // 0..351
      int p = rr - RMAX;                      // -40..311
      int srow = 255 - abs(255 - abs(p));     // reflect (valid for |p| <= 510)
      float4 v = *reinterpret_cast<const float4*>(src + srow * W + c4);
      int rc = rr & ~3, rl = rr & 3;
      tile[(c4 + 0) * 352 + (rc ^ (((c4 + 0) & 7) << 2)) + rl] = v.x;
      tile[(c4 + 1) * 352 + (rc ^ (((c4 + 1) & 7) << 2)) + rl] = v.y;
      tile[(c4 + 2) * 352 + (rc ^ (((c4 + 2) & 7) << 2)) + rl] = v.z;
      tile[(c4 + 3) * 352 + (rc ^ (((c4 + 3) & 7) << 2)) + rl] = v.w;
    }
  }
  __syncthreads();
  int col = tid & 31;
  int rgrp = tid >> 5;                        // 0..7
  int h0 = rgrp << 4;                         // window A rows h0..h0+15; B = +128
  int nIter = (L + d + 30) & ~15;             // >= L+d+15: covers j=L-1 for o=15
  int A = h0 + ((RMAX - R) & ~3);             // aligned sweep start (tile coords)
  int cb = col * 352;
  int swz = (col & 7) << 2;
  float accA[16], accB[16], kq[16];
#pragma unroll
  for (int o = 0; o < 16; ++o) { accA[o] = 0.f; accB[o] = 0.f; kq[o] = 0.f; }
  for (int jb = 0; jb < nIter; jb += 16) {
    float kn[16];
#pragma unroll
    for (int u = 0; u < 16; ++u) kn[u] = kt[jb + u];   // uniform -> s_load
    float va[16], vb[16];
#pragma unroll
    for (int m = 0; m < 4; ++m) {
      int qa = A + jb + (m << 2);             // mult of 4
      float4 ta = *reinterpret_cast<const float4*>(&tile[cb + (qa ^ swz)]);
      float4 tb = *reinterpret_cast<const float4*>(&tile[cb + ((qa + 128) ^ swz)]);
      va[4 * m + 0] = ta.x; va[4 * m + 1] = ta.y; va[4 * m + 2] = ta.z; va[4 * m + 3] = ta.w;
      vb[4 * m + 0] = tb.x; vb[4 * m + 1] = tb.y; vb[4 * m + 2] = tb.z; vb[4 * m + 3] = tb.w;
    }
#pragma unroll
    for (int u = 0; u < 16; ++u) {
      kq[u] = kn[u];
#pragma unroll
      for (int o = 0; o < 16; ++o) {
        float k = kq[(u - o) & 15];
        accA[o] += k * va[u];
        accB[o] += k * vb[u];
      }
    }
  }
#pragma unroll
  for (int o = 0; o < 16; ++o) {
    dst[(h0 + o) * W + col] = accA[o];
    dst[(h0 + 128 + o) * W + col] = accB[o];
  }
}

// W-pass (r14 BEST-MEASURED, verbatim): tile[32][361] (stride coprime to 32 ->
// conflict-free same-col reads), taps broadcast from ktile LDS, dual g-loop,
// float4 stores, (256,3), grid (8,192).
__global__ __launch_bounds__(256, 3) void wpass_split(const float* __restrict__ srcbuf,
                                                      const int* __restrict__ t,
                                                      const float* __restrict__ ktab,
                                                      const int* __restrict__ ord,
                                                      const int* __restrict__ rtab,
                                                      float* __restrict__ dstbuf) {
  __shared__ float tile[32 * 361];
  __shared__ float ktile[256];
  int tid = threadIdx.x;
  int img = __builtin_amdgcn_readfirstlane(ord[blockIdx.y]);
  int ht = blockIdx.x;                        // 0..7
  int b = img / 3;
  int tv = __builtin_amdgcn_readfirstlane(min(max(t[b], 0), 19));
  int R = __builtin_amdgcn_readfirstlane(rtab[tv]);
  int L = 2 * R + 1;
  const float* __restrict__ kt = ktab + tv * 256;
  const float* src = srcbuf + (size_t)img * IMG + (ht << 5) * W;
  float* dst = dstbuf + (size_t)img * IMG + (ht << 5) * W;
  ktile[tid] = kt[tid];                       // tap row -> LDS (1 KB)
  {
    int srow = tid >> 3;                      // 0..31
    int jbase = tid & 7;
    const float* sp = src + srow * W;
    float* tp0 = &tile[srow * 361];
#pragma unroll
    for (int k = 0; k < 11; ++k) {
      int j = jbase + (k << 3);               // 0..87
      int c0 = -RMAX + (j << 2);              // -40..308
      float* tp = tp0 + c0 + RMAX;
      if (c0 >= 0 && c0 <= 252) {
        float4 v = *reinterpret_cast<const float4*>(sp + c0);
        tp[0] = v.x; tp[1] = v.y; tp[2] = v.z; tp[3] = v.w;
      } else {
#pragma unroll
        for (int d = 0; d < 4; ++d) {
          int cc = c0 + d;
          int rc = 255 - abs(255 - abs(cc));  // reflect
          tp[d] = sp[rc];
        }
      }
    }
  }
  __syncthreads();
  int row = tid & 31;
  int wgrp = tid >> 5;                        // 0..7
  int rowbase = row * 361;
  int nIter = (L + 30) & ~15;
  for (int g = 0; g < 2; ++g) {
    int w0 = (wgrp << 5) + (g << 4);
    float acc[16];
    float kq[16];
#pragma unroll
    for (int o = 0; o < 16; ++o) { acc[o] = 0.f; kq[o] = 0.f; }
    int pb = w0 - R + RMAX;                   // tile-col base (>= 0; reads <= 350 < 361)
    for (int jb = 0; jb < nIter; jb += 16) {
#pragma unroll
      for (int u = 0; u < 16; ++u) {
        kq[u] = ktile[jb + u + 8];            // uniform addr -> LDS broadcast
        float v = tile[rowbase + pb + jb + u];
#pragma unroll
        for (int o = 0; o < 16; ++o) acc[o] += kq[(u - o) & 15] * v;
      }
    }
    float4 v0 = make_float4(acc[0], acc[1], acc[2], acc[3]);
    float4 v1 = make_float4(acc[4], acc[5], acc[6], acc[7]);
    float4 v2 = make_float4(acc[8], acc[9], acc[10], acc[11]);
    float4 v3 = make_float4(acc[12], acc[13], acc[14], acc[15]);
    float* o0 = dst + row * W + w0;
    *reinterpret_cast<float4*>(o0 + 0) = v0;
    *reinterpret_cast<float4*>(o0 + 4) = v1;
    *reinterpret_cast<float4*>(o0 + 8) = v2;
    *reinterpret_cast<float4*>(o0 + 12) = v3;
  }
}

// Fallback in-place W-pass (only if ws too small; same structure, io buffer).
__global__ __launch_bounds__(256, 3) void wpass_inplace(const int* __restrict__ t,
                                                        const float* __restrict__ ktab,
                                                        const int* __restrict__ ord,
                                                        const int* __restrict__ rtab,
                                                        float* __restrict__ io) {
  __shared__ float tile[32 * 361];
  __shared__ float ktile[256];
  int tid = threadIdx.x;
  int img = __builtin_amdgcn_readfirstlane(ord[blockIdx.y]);
  int ht = blockIdx.x;                        // 0..7
  int b = img / 3;
  int tv = __builtin_amdgcn_readfirstlane(min(max(t[b], 0), 19));
  int R = __builtin_amdgcn_readfirstlane(rtab[tv]);
  int L = 2 * R + 1;
  const float* __restrict__ kt = ktab + tv * 256;
  float* basep = io + (size_t)img * IMG + (ht << 5) * W;
  ktile[tid] = kt[tid];
  {
    int srow = tid >> 3;
    int jbase = tid & 7;
    const float* sp = basep + srow * W;
    float* tp0 = &tile[srow * 361];
#pragma unroll
    for (int k = 0; k < 11; ++k) {
      int j = jbase + (k << 3);
      int c0 = -RMAX + (j << 2);
      float* tp = tp0 + c0 + RMAX;
      if (c0 >= 0 && c0 <= 252) {
        float4 v = *reinterpret_cast<const float4*>(sp + c0);
        tp[0] = v.x; tp[1] = v.y; tp[2] = v.z; tp[3] = v.w;
      } else {
#pragma unroll
        for (int d = 0; d < 4; ++d) {
          int cc = c0 + d;
          int rc = 255 - abs(255 - abs(cc));
          tp[d] = sp[rc];
        }
      }
    }
  }
  __syncthreads();
  int row = tid & 31;
  int wgrp = tid >> 5;
  int rowbase = row * 361;
  int nIter = (L + 30) & ~15;
  for (int g = 0; g < 2; ++g) {
    int w0 = (wgrp << 5) + (g << 4);
    float acc[16];
    float kq[16];
#pragma unroll
    for (int o = 0; o < 16; ++o) { acc[o] = 0.f; kq[o] = 0.f; }
    int pb = w0 - R + RMAX;
    for (int jb = 0; jb < nIter; jb += 16) {
#pragma unroll
      for (int u = 0; u < 16; ++u) {
        kq[u] = ktile[jb + u + 8];
        float v = tile[rowbase + pb + jb + u];
#pragma unroll
        for (int o = 0; o < 16; ++o) acc[o] += kq[(u - o) & 15] * v;
      }
    }
    float4 v0 = make_float4(acc[0], acc[1], acc[2], acc[3]);
    float4 v1 = make_float4(acc[4], acc[5], acc[6], acc[7]);
    float4 v2 = make_float4(acc[8], acc[9], acc[10], acc[11]);
    float4 v3 = make_float4(acc[12], acc[13], acc[14], acc[15]);
    float* o0 = basep + row * W + w0;
    *reinterpret_cast<float4*>(o0 + 0) = v0;
    *reinterpret_cast<float4*>(o0 + 4) = v1;
    *reinterpret_cast<float4*>(o0 + 8) = v2;
    *reinterpret_cast<float4*>(o0 + 12) = v3;
  }
}

extern "C" void kernel_launch(void* const* d_in, const int* in_sizes, int n_in,
                              void* d_out, int out_size, void* d_ws, size_t ws_size,
                              hipStream_t stream) {
  const float* x = (const float*)d_in[0];
  const int* t = (const int*)d_in[1];
  float* out = (float*)d_out;
  float* ktab = (float*)d_ws;
  int* ord = (int*)((char*)d_ws + 20480);
  int* rtab = (int*)((char*)d_ws + 21248);
  const size_t mid_off = 32768;
  const size_t mid_bytes = (size_t)192 * IMG * 4;

  hipLaunchKernelGGL(init_kernel, dim3(20), dim3(256), 0, stream, t, ktab, ord, rtab);
  if (ws_size >= mid_off + mid_bytes) {
    float* mid = (float*)((char*)d_ws + mid_off);
    hipLaunchKernelGGL(hpass_kernel, dim3(8, 192), dim3(256), 0, stream, x, t, ktab, ord, rtab, mid);
    hipLaunchKernelGGL(wpass_split, dim3(8, 192), dim3(256), 0, stream, mid, t, ktab, ord, rtab, out);
  } else {
    hipLaunchKernelGGL(hpass_kernel, dim3(8, 192), dim3(256), 0, stream, x, t, ktab, ord, rtab, out);
    hipLaunchKernelGGL(wpass_inplace, dim3(8, 192), dim3(256), 0, stream, t, ktab, ord, rtab, out);
  }
}